// Round 1
// baseline (640.020 us; speedup 1.0000x reference)
//
#include <hip/hip_runtime.h>
#include <hip/hip_bf16.h>

// ---------------------------------------------------------------------------
// BGE-M3 style scoring: dense (CLS cosine), sparse (scatter-max vocab dot),
// colbert (maxsim).  Shapes: q_hidden [8,128,1024], p_hidden [64,512,1024].
// Out = concat(dense[8,64], sparse[8,64], colbert[8,64]) fp32.
// ---------------------------------------------------------------------------

typedef __bf16 bf16x8 __attribute__((ext_vector_type(8)));
typedef float floatx4 __attribute__((ext_vector_type(4)));

#define TEMP 0.02f

__device__ __forceinline__ unsigned short f2bf(float f) {
    unsigned u = __float_as_uint(f);
    unsigned r = (u + 0x7FFFu + ((u >> 16) & 1u)) >> 16;  // RNE
    return (unsigned short)r;
}
__device__ __forceinline__ float bf2f(unsigned short h) {
    return __uint_as_float(((unsigned)h) << 16);
}
// order-preserving float<->uint encode for atomicMax on possibly-negative floats
__device__ __forceinline__ unsigned encf(float f) {
    unsigned u = __float_as_uint(f);
    return (u & 0x80000000u) ? ~u : (u | 0x80000000u);
}
__device__ __forceinline__ float decf(unsigned u) {
    return __uint_as_float((u & 0x80000000u) ? (u & 0x7FFFFFFFu) : ~u);
}

__device__ __forceinline__ void async_load16(void* lds, const void* g) {
    __builtin_amdgcn_global_load_lds(
        (__attribute__((address_space(1))) void*)g,
        (__attribute__((address_space(3))) void*)lds,
        16, 0, 0);
}

// ---------------------------------------------------------------------------
// fp32 -> bf16 elementwise (for colbert_w)
// ---------------------------------------------------------------------------
__global__ void conv_only(const float* __restrict__ src, unsigned short* __restrict__ dst, int n4)
{
    int i = blockIdx.x * blockDim.x + threadIdx.x;
    if (i < n4) {
        float4 x = ((const float4*)src)[i];
        ushort4 o;
        o.x = f2bf(x.x); o.y = f2bf(x.y); o.z = f2bf(x.z); o.w = f2bf(x.w);
        ((ushort4*)dst)[i] = o;
    }
}

// ---------------------------------------------------------------------------
// per hidden row: fp32 -> bf16 copy + sparse token weight
//   tw[row] = relu(dot(hidden[row], sparse_w) + sparse_b)   (fp32 accuracy)
// one block (256 thr) per row of 1024
// ---------------------------------------------------------------------------
__global__ void conv_tw(const float* __restrict__ src, unsigned short* __restrict__ dst,
                        const float* __restrict__ sw, const float* __restrict__ sb,
                        float* __restrict__ tw)
{
    __shared__ float red[4];
    int row = blockIdx.x;
    int t = threadIdx.x;
    const float4* s4 = (const float4*)(src + (size_t)row * 1024);
    const float4* w4 = (const float4*)sw;
    float4 x = s4[t];
    float4 w = w4[t];
    ushort4 o;
    o.x = f2bf(x.x); o.y = f2bf(x.y); o.z = f2bf(x.z); o.w = f2bf(x.w);
    ((ushort4*)dst)[(size_t)row * 256 + t] = o;
    float acc = x.x * w.x + x.y * w.y + x.z * w.z + x.w * w.w;
    #pragma unroll
    for (int s = 32; s; s >>= 1) acc += __shfl_down(acc, s, 64);
    if ((t & 63) == 0) red[t >> 6] = acc;
    __syncthreads();
    if (t == 0) {
        float v = red[0] + red[1] + red[2] + red[3] + sb[0];
        tw[row] = fmaxf(v, 0.0f);
    }
}

// ---------------------------------------------------------------------------
// 128x128x(K) bf16 MFMA GEMM, B^T layout:  C[m,n] = sum_k A[m,k]*B[n,k]
// MODE 0: C_bf16[m,n] = result + bias[n]          (projection)
// MODE 1: fused epilogue: atomicMax of per-(row, p-batch) max, excluding
//         CLS columns (global col % 512 == 0)     (maxsim)
// block = 256 thr (4 waves, 2x2), tile 128x128, BK=32
// ---------------------------------------------------------------------------
template<int MODE>
__global__ __launch_bounds__(256, 2)
void gemm_bt(const unsigned short* __restrict__ A,
             const unsigned short* __restrict__ B,
             const float* __restrict__ bias,
             unsigned short* __restrict__ C,
             unsigned* __restrict__ Mbuf,
             int M, int N, int K)
{
    __shared__ unsigned short smA[128 * 32];
    __shared__ unsigned short smB[128 * 32];
    const int tid  = threadIdx.x;
    const int lane = tid & 63;
    const int w    = tid >> 6;
    const int wm   = w >> 1, wn = w & 1;
    const int quad = lane >> 4, m16 = lane & 15;
    const int rowBase = blockIdx.y * 128;
    const int colBase = blockIdx.x * 128;

    // staging: tile rows 16c..16c+15 per 1024B chunk; wave w does chunks {w, w+4}
    const unsigned short* aG0 = A + (long long)(rowBase + w * 16 + (lane >> 2)) * K + (lane & 3) * 8;
    const unsigned short* aG1 = aG0 + 64LL * K;
    const unsigned short* bG0 = B + (long long)(colBase + w * 16 + (lane >> 2)) * K + (lane & 3) * 8;
    const unsigned short* bG1 = bG0 + 64LL * K;
    unsigned short* lA0 = smA + w * 512;
    unsigned short* lA1 = smA + (w + 4) * 512;
    unsigned short* lB0 = smB + w * 512;
    unsigned short* lB1 = smB + (w + 4) * 512;

    floatx4 acc[4][4] = {};

    for (int k0 = 0; k0 < K; k0 += 32) {
        async_load16(lA0, aG0 + k0);
        async_load16(lA1, aG1 + k0);
        async_load16(lB0, bG0 + k0);
        async_load16(lB1, bG1 + k0);
        __syncthreads();
        bf16x8 af[4], bfr[4];
        #pragma unroll
        for (int f = 0; f < 4; ++f) {
            af[f]  = *(const bf16x8*)(smA + (wm * 64 + f * 16 + m16) * 32 + quad * 8);
            bfr[f] = *(const bf16x8*)(smB + (wn * 64 + f * 16 + m16) * 32 + quad * 8);
        }
        #pragma unroll
        for (int i = 0; i < 4; ++i)
            #pragma unroll
            for (int j = 0; j < 4; ++j)
                acc[i][j] = __builtin_amdgcn_mfma_f32_16x16x32_bf16(af[i], bfr[j], acc[i][j], 0, 0, 0);
        __syncthreads();
    }

    if (MODE == 0) {
        float bcol[4];
        #pragma unroll
        for (int j = 0; j < 4; ++j) bcol[j] = bias[colBase + wn * 64 + j * 16 + m16];
        #pragma unroll
        for (int i = 0; i < 4; ++i) {
            int row0 = rowBase + wm * 64 + i * 16 + quad * 4;
            #pragma unroll
            for (int r = 0; r < 4; ++r) {
                #pragma unroll
                for (int j = 0; j < 4; ++j) {
                    int col = colBase + wn * 64 + j * 16 + m16;
                    C[(long long)(row0 + r) * N + col] = f2bf(acc[i][j][r] + bcol[j]);
                }
            }
        }
    } else {
        const int pb = colBase >> 9;  // 512 p-tokens per passage
        #pragma unroll
        for (int i = 0; i < 4; ++i) {
            #pragma unroll
            for (int r = 0; r < 4; ++r) {
                float mx = -3.0e38f;
                #pragma unroll
                for (int j = 0; j < 4; ++j) {
                    int colg = colBase + wn * 64 + j * 16 + m16;
                    float v = acc[i][j][r];
                    if ((colg & 511) == 0) v = -3.0e38f;  // exclude CLS column
                    mx = fmaxf(mx, v);
                }
                // max across the 16 lanes of the m16 dimension
                #pragma unroll
                for (int s = 1; s < 16; s <<= 1) mx = fmaxf(mx, __shfl_xor(mx, s, 64));
                if (m16 == 0) {
                    int row = rowBase + wm * 64 + i * 16 + quad * 4 + r;
                    atomicMax(&Mbuf[row * 64 + pb], encf(mx));
                }
            }
        }
    }
}

// ---------------------------------------------------------------------------
// in-place row L2-normalize of bf16 rows (with mask): v = v*m / max(||v*m||,1e-12)
// ---------------------------------------------------------------------------
__global__ void normalize_rows_k(unsigned short* __restrict__ V, const float* __restrict__ mask)
{
    __shared__ float red[4];
    __shared__ float sscale;
    int row = blockIdx.x;
    int t = threadIdx.x;
    float m = mask[row];
    ushort4* v4 = (ushort4*)(V + (size_t)row * 1024);
    ushort4 x = v4[t];
    float f0 = bf2f(x.x) * m, f1 = bf2f(x.y) * m, f2 = bf2f(x.z) * m, f3 = bf2f(x.w) * m;
    float s = f0 * f0 + f1 * f1 + f2 * f2 + f3 * f3;
    #pragma unroll
    for (int sh = 32; sh; sh >>= 1) s += __shfl_down(s, sh, 64);
    if ((t & 63) == 0) red[t >> 6] = s;
    __syncthreads();
    if (t == 0) {
        float n = sqrtf(red[0] + red[1] + red[2] + red[3]);
        sscale = 1.0f / fmaxf(n, 1e-12f);
    }
    __syncthreads();
    float sc = sscale;
    x.x = f2bf(f0 * sc); x.y = f2bf(f1 * sc); x.z = f2bf(f2 * sc); x.w = f2bf(f3 * sc);
    v4[t] = x;
}

// ---------------------------------------------------------------------------
// colbert final reduce: out = sum_{i=1..127} dec(M[i,pb]) / masksum / TEMP
// one wave per (qb,pb) pair
// ---------------------------------------------------------------------------
__global__ void colbert_reduce_k(const unsigned* __restrict__ Mbuf,
                                 const float* __restrict__ q_mask,
                                 float* __restrict__ out)
{
    int pair = blockIdx.x * 4 + (threadIdx.x >> 6);
    int lane = threadIdx.x & 63;
    int qb = pair >> 6, pb = pair & 63;
    float s = 0.0f, msum = 0.0f;
    for (int i = 1 + lane; i < 128; i += 64) {
        s += decf(Mbuf[(qb * 128 + i) * 64 + pb]);
        msum += q_mask[qb * 128 + i];
    }
    #pragma unroll
    for (int sh = 32; sh; sh >>= 1) {
        s += __shfl_down(s, sh, 64);
        msum += __shfl_down(msum, sh, 64);
    }
    if (lane == 0) out[1024 + qb * 64 + pb] = s / msum / TEMP;
}

// ---------------------------------------------------------------------------
// dense: cosine of CLS tokens, fp32 exact. one block per (qb,pb)
// ---------------------------------------------------------------------------
__global__ void dense_scores_k(const float* __restrict__ qh, const float* __restrict__ ph,
                               float* __restrict__ out)
{
    __shared__ float red[12];
    int qb = blockIdx.x >> 6, pb = blockIdx.x & 63;
    int t = threadIdx.x;
    const float4* q4 = (const float4*)(qh + (size_t)qb * 128 * 1024);
    const float4* p4 = (const float4*)(ph + (size_t)pb * 512 * 1024);
    float4 a = q4[t], b = p4[t];
    float dot = a.x * b.x + a.y * b.y + a.z * b.z + a.w * b.w;
    float nq  = a.x * a.x + a.y * a.y + a.z * a.z + a.w * a.w;
    float np  = b.x * b.x + b.y * b.y + b.z * b.z + b.w * b.w;
    #pragma unroll
    for (int sh = 32; sh; sh >>= 1) {
        dot += __shfl_down(dot, sh, 64);
        nq  += __shfl_down(nq, sh, 64);
        np  += __shfl_down(np, sh, 64);
    }
    if ((t & 63) == 0) { int w = t >> 6; red[w] = dot; red[4 + w] = nq; red[8 + w] = np; }
    __syncthreads();
    if (t == 0) {
        dot = red[0] + red[1] + red[2] + red[3];
        nq  = red[4] + red[5] + red[6] + red[7];
        np  = red[8] + red[9] + red[10] + red[11];
        out[qb * 64 + pb] = dot / (fmaxf(sqrtf(nq), 1e-12f) * fmaxf(sqrtf(np), 1e-12f)) / TEMP;
    }
}

// ---------------------------------------------------------------------------
// sparse canonicalization: eff[row,l] = tw if token l is the (unique) argmax
// for its id within the row (ties -> lowest index) and id not in {0,1,2,3}
// one block per row
// ---------------------------------------------------------------------------
__global__ void sparse_canon(const int* __restrict__ ids, const float* __restrict__ tw,
                             float* __restrict__ eff, int L)
{
    __shared__ int   sid[512];
    __shared__ float stw[512];
    int row = blockIdx.x;
    int t = threadIdx.x;
    for (int l = t; l < L; l += 256) { sid[l] = ids[row * L + l]; stw[l] = tw[row * L + l]; }
    __syncthreads();
    for (int l = t; l < L; l += 256) {
        int id = sid[l];
        float wv = stw[l];
        bool canon = (id >= 4);  // UNUSED ids {0,1,2,3} zeroed
        if (canon) {
            for (int m = 0; m < L; ++m) {
                if (m != l && sid[m] == id) {
                    float wm = stw[m];
                    if (wm > wv || (wm == wv && m < l)) { canon = false; break; }
                }
            }
        }
        eff[row * L + l] = canon ? wv : 0.0f;
    }
}

// ---------------------------------------------------------------------------
// sparse scores: sum over matching ids of q_eff * p_eff, one block per pair
// ---------------------------------------------------------------------------
__global__ void sparse_scores_k(const int* __restrict__ q_ids, const float* __restrict__ q_eff,
                                const int* __restrict__ p_ids, const float* __restrict__ p_eff,
                                float* __restrict__ out)
{
    __shared__ int   qid[128];
    __shared__ float qef[128];
    __shared__ int   pid[512];
    __shared__ float pef[512];
    __shared__ float red[4];
    int qb = blockIdx.x >> 6, pb = blockIdx.x & 63;
    int t = threadIdx.x;
    if (t < 128) { qid[t] = q_ids[qb * 128 + t]; qef[t] = q_eff[qb * 128 + t]; }
    for (int m = t; m < 512; m += 256) { pid[m] = p_ids[pb * 512 + m]; pef[m] = p_eff[pb * 512 + m]; }
    __syncthreads();
    float s = 0.0f;
    for (int idx = t; idx < 128 * 512; idx += 256) {
        int l = idx >> 9, m = idx & 511;
        if (qid[l] == pid[m]) s += qef[l] * pef[m];
    }
    #pragma unroll
    for (int sh = 32; sh; sh >>= 1) s += __shfl_down(s, sh, 64);
    if ((t & 63) == 0) red[t >> 6] = s;
    __syncthreads();
    if (t == 0) out[512 + qb * 64 + pb] = (red[0] + red[1] + red[2] + red[3]) / TEMP;
}

// ---------------------------------------------------------------------------
extern "C" void kernel_launch(void* const* d_in, const int* in_sizes, int n_in,
                              void* d_out, int out_size, void* d_ws, size_t ws_size,
                              hipStream_t stream)
{
    const float* q_hidden = (const float*)d_in[0];   // [8,128,1024]
    const float* p_hidden = (const float*)d_in[1];   // [64,512,1024]
    const float* q_mask   = (const float*)d_in[2];   // [8,128]
    const float* p_mask   = (const float*)d_in[3];   // [64,512]
    const int*   q_ids    = (const int*)d_in[4];     // [8,128]
    const int*   p_ids    = (const int*)d_in[5];     // [64,512]
    const float* colbert_w = (const float*)d_in[6];  // [1024,1024]
    const float* colbert_b = (const float*)d_in[7];  // [1024]
    const float* sparse_w  = (const float*)d_in[8];  // [1024]
    const float* sparse_b  = (const float*)d_in[9];  // [1]
    float* out = (float*)d_out;                      // [3*512]

    // workspace carve-up (~141 MB)
    char* ws = (char*)d_ws;
    size_t off = 0;
    auto carve = [&](size_t bytes) { char* p = ws + off; off += (bytes + 255) & ~(size_t)255; return p; };
    unsigned short* Wb   = (unsigned short*)carve((size_t)1024 * 1024 * 2);
    unsigned short* qhb  = (unsigned short*)carve((size_t)1024 * 1024 * 2);
    unsigned short* phb  = (unsigned short*)carve((size_t)32768 * 1024 * 2);
    unsigned short* qv   = (unsigned short*)carve((size_t)1024 * 1024 * 2);
    unsigned short* pv   = (unsigned short*)carve((size_t)32768 * 1024 * 2);
    float*    tw_q  = (float*)carve(1024 * 4);
    float*    tw_p  = (float*)carve(32768 * 4);
    float*    eff_q = (float*)carve(1024 * 4);
    float*    eff_p = (float*)carve(32768 * 4);
    unsigned* Mbuf  = (unsigned*)carve((size_t)1024 * 64 * 4);

    hipMemsetAsync(Mbuf, 0, (size_t)1024 * 64 * 4, stream);

    // bf16 conversions + sparse token weights
    conv_only<<<1024, 256, 0, stream>>>(colbert_w, Wb, 262144);
    conv_tw<<<1024, 256, 0, stream>>>(q_hidden, qhb, sparse_w, sparse_b, tw_q);
    conv_tw<<<32768, 256, 0, stream>>>(p_hidden, phb, sparse_w, sparse_b, tw_p);

    // colbert projection GEMMs: V = X @ W^T + b   (bf16 out)
    gemm_bt<0><<<dim3(8, 8), 256, 0, stream>>>(qhb, Wb, colbert_b, qv, nullptr, 1024, 1024, 1024);
    gemm_bt<0><<<dim3(8, 256), 256, 0, stream>>>(phb, Wb, colbert_b, pv, nullptr, 32768, 1024, 1024);

    // mask + L2 normalize rows in place
    normalize_rows_k<<<1024, 256, 0, stream>>>(qv, q_mask);
    normalize_rows_k<<<32768, 256, 0, stream>>>(pv, p_mask);

    // maxsim GEMM with fused max epilogue
    gemm_bt<1><<<dim3(256, 8), 256, 0, stream>>>(qv, pv, nullptr, nullptr, Mbuf, 1024, 32768, 1024);
    colbert_reduce_k<<<128, 256, 0, stream>>>(Mbuf, q_mask, out);

    // dense
    dense_scores_k<<<512, 256, 0, stream>>>(q_hidden, p_hidden, out);

    // sparse
    sparse_canon<<<8, 256, 0, stream>>>(q_ids, tw_q, eff_q, 128);
    sparse_canon<<<64, 256, 0, stream>>>(p_ids, tw_p, eff_p, 512);
    sparse_scores_k<<<512, 256, 0, stream>>>(q_ids, eff_q, p_ids, eff_p, out);
}

// Round 2
// 519.208 us; speedup vs baseline: 1.2327x; 1.2327x over previous
//
#include <hip/hip_runtime.h>
#include <hip/hip_bf16.h>

// ---------------------------------------------------------------------------
// BGE-M3 style scoring: dense (CLS cosine), sparse (scatter-max vocab dot),
// colbert (maxsim).  Shapes: q_hidden [8,128,1024], p_hidden [64,512,1024].
// Out = concat(dense[8,64], sparse[8,64], colbert[8,64]) fp32.
// ---------------------------------------------------------------------------

typedef __bf16 bf16x8 __attribute__((ext_vector_type(8)));
typedef float floatx4 __attribute__((ext_vector_type(4)));

#define TEMP 0.02f

__device__ __forceinline__ unsigned short f2bf(float f) {
    unsigned u = __float_as_uint(f);
    unsigned r = (u + 0x7FFFu + ((u >> 16) & 1u)) >> 16;  // RNE
    return (unsigned short)r;
}
__device__ __forceinline__ float bf2f(unsigned short h) {
    return __uint_as_float(((unsigned)h) << 16);
}
// order-preserving float<->uint encode for atomicMax on possibly-negative floats
__device__ __forceinline__ unsigned encf(float f) {
    unsigned u = __float_as_uint(f);
    return (u & 0x80000000u) ? ~u : (u | 0x80000000u);
}
__device__ __forceinline__ float decf(unsigned u) {
    return __uint_as_float((u & 0x80000000u) ? (u & 0x7FFFFFFFu) : ~u);
}

__device__ __forceinline__ void async_load16(void* lds, const void* g) {
    __builtin_amdgcn_global_load_lds(
        (__attribute__((address_space(1))) void*)g,
        (__attribute__((address_space(3))) void*)lds,
        16, 0, 0);
}

// ---------------------------------------------------------------------------
// fp32 -> bf16 elementwise (for colbert_w)
// ---------------------------------------------------------------------------
__global__ void conv_only(const float* __restrict__ src, unsigned short* __restrict__ dst, int n4)
{
    int i = blockIdx.x * blockDim.x + threadIdx.x;
    if (i < n4) {
        float4 x = ((const float4*)src)[i];
        ushort4 o;
        o.x = f2bf(x.x); o.y = f2bf(x.y); o.z = f2bf(x.z); o.w = f2bf(x.w);
        ((ushort4*)dst)[i] = o;
    }
}

// ---------------------------------------------------------------------------
// per hidden row: fp32 -> bf16 copy + sparse token weight
//   tw[row] = relu(dot(hidden[row], sparse_w) + sparse_b)   (fp32 accuracy)
// one block (256 thr) per row of 1024
// ---------------------------------------------------------------------------
__global__ void conv_tw(const float* __restrict__ src, unsigned short* __restrict__ dst,
                        const float* __restrict__ sw, const float* __restrict__ sb,
                        float* __restrict__ tw)
{
    __shared__ float red[4];
    int row = blockIdx.x;
    int t = threadIdx.x;
    const float4* s4 = (const float4*)(src + (size_t)row * 1024);
    const float4* w4 = (const float4*)sw;
    float4 x = s4[t];
    float4 w = w4[t];
    ushort4 o;
    o.x = f2bf(x.x); o.y = f2bf(x.y); o.z = f2bf(x.z); o.w = f2bf(x.w);
    ((ushort4*)dst)[(size_t)row * 256 + t] = o;
    float acc = x.x * w.x + x.y * w.y + x.z * w.z + x.w * w.w;
    #pragma unroll
    for (int s = 32; s; s >>= 1) acc += __shfl_down(acc, s, 64);
    if ((t & 63) == 0) red[t >> 6] = acc;
    __syncthreads();
    if (t == 0) {
        float v = red[0] + red[1] + red[2] + red[3] + sb[0];
        tw[row] = fmaxf(v, 0.0f);
    }
}

// ---------------------------------------------------------------------------
// 128x128x(K) bf16 MFMA GEMM, B^T layout:  C[m,n] = sum_k A[m,k]*B[n,k]
// MODE 0: C_bf16[m,n] = result + bias[n]          (projection)
// MODE 1: fused epilogue: atomicMax of per-(row, p-batch) max, excluding
//         CLS columns (global col % 512 == 0)     (maxsim)
// block = 256 thr (4 waves, 2x2), tile 128x128, BK=32
// ---------------------------------------------------------------------------
template<int MODE>
__global__ __launch_bounds__(256, 2)
void gemm_bt(const unsigned short* __restrict__ A,
             const unsigned short* __restrict__ B,
             const float* __restrict__ bias,
             unsigned short* __restrict__ C,
             unsigned* __restrict__ Mbuf,
             int M, int N, int K)
{
    __shared__ unsigned short smA[128 * 32];
    __shared__ unsigned short smB[128 * 32];
    const int tid  = threadIdx.x;
    const int lane = tid & 63;
    const int w    = tid >> 6;
    const int wm   = w >> 1, wn = w & 1;
    const int quad = lane >> 4, m16 = lane & 15;
    const int rowBase = blockIdx.y * 128;
    const int colBase = blockIdx.x * 128;

    // staging: tile rows 16c..16c+15 per 1024B chunk; wave w does chunks {w, w+4}
    const unsigned short* aG0 = A + (long long)(rowBase + w * 16 + (lane >> 2)) * K + (lane & 3) * 8;
    const unsigned short* aG1 = aG0 + 64LL * K;
    const unsigned short* bG0 = B + (long long)(colBase + w * 16 + (lane >> 2)) * K + (lane & 3) * 8;
    const unsigned short* bG1 = bG0 + 64LL * K;
    unsigned short* lA0 = smA + w * 512;
    unsigned short* lA1 = smA + (w + 4) * 512;
    unsigned short* lB0 = smB + w * 512;
    unsigned short* lB1 = smB + (w + 4) * 512;

    floatx4 acc[4][4] = {};

    for (int k0 = 0; k0 < K; k0 += 32) {
        async_load16(lA0, aG0 + k0);
        async_load16(lA1, aG1 + k0);
        async_load16(lB0, bG0 + k0);
        async_load16(lB1, bG1 + k0);
        __syncthreads();
        bf16x8 af[4], bfr[4];
        #pragma unroll
        for (int f = 0; f < 4; ++f) {
            af[f]  = *(const bf16x8*)(smA + (wm * 64 + f * 16 + m16) * 32 + quad * 8);
            bfr[f] = *(const bf16x8*)(smB + (wn * 64 + f * 16 + m16) * 32 + quad * 8);
        }
        #pragma unroll
        for (int i = 0; i < 4; ++i)
            #pragma unroll
            for (int j = 0; j < 4; ++j)
                acc[i][j] = __builtin_amdgcn_mfma_f32_16x16x32_bf16(af[i], bfr[j], acc[i][j], 0, 0, 0);
        __syncthreads();
    }

    if (MODE == 0) {
        float bcol[4];
        #pragma unroll
        for (int j = 0; j < 4; ++j) bcol[j] = bias[colBase + wn * 64 + j * 16 + m16];
        #pragma unroll
        for (int i = 0; i < 4; ++i) {
            int row0 = rowBase + wm * 64 + i * 16 + quad * 4;
            #pragma unroll
            for (int r = 0; r < 4; ++r) {
                #pragma unroll
                for (int j = 0; j < 4; ++j) {
                    int col = colBase + wn * 64 + j * 16 + m16;
                    C[(long long)(row0 + r) * N + col] = f2bf(acc[i][j][r] + bcol[j]);
                }
            }
        }
    } else {
        const int pb = colBase >> 9;  // 512 p-tokens per passage
        #pragma unroll
        for (int i = 0; i < 4; ++i) {
            #pragma unroll
            for (int r = 0; r < 4; ++r) {
                float mx = -3.0e38f;
                #pragma unroll
                for (int j = 0; j < 4; ++j) {
                    int colg = colBase + wn * 64 + j * 16 + m16;
                    float v = acc[i][j][r];
                    if ((colg & 511) == 0) v = -3.0e38f;  // exclude CLS column
                    mx = fmaxf(mx, v);
                }
                // max across the 16 lanes of the m16 dimension
                #pragma unroll
                for (int s = 1; s < 16; s <<= 1) mx = fmaxf(mx, __shfl_xor(mx, s, 64));
                if (m16 == 0) {
                    int row = rowBase + wm * 64 + i * 16 + quad * 4 + r;
                    atomicMax(&Mbuf[row * 64 + pb], encf(mx));
                }
            }
        }
    }
}

// ---------------------------------------------------------------------------
// in-place row L2-normalize of bf16 rows (with mask): v = v*m / max(||v*m||,1e-12)
// ---------------------------------------------------------------------------
__global__ void normalize_rows_k(unsigned short* __restrict__ V, const float* __restrict__ mask)
{
    __shared__ float red[4];
    __shared__ float sscale;
    int row = blockIdx.x;
    int t = threadIdx.x;
    float m = mask[row];
    ushort4* v4 = (ushort4*)(V + (size_t)row * 1024);
    ushort4 x = v4[t];
    float f0 = bf2f(x.x) * m, f1 = bf2f(x.y) * m, f2 = bf2f(x.z) * m, f3 = bf2f(x.w) * m;
    float s = f0 * f0 + f1 * f1 + f2 * f2 + f3 * f3;
    #pragma unroll
    for (int sh = 32; sh; sh >>= 1) s += __shfl_down(s, sh, 64);
    if ((t & 63) == 0) red[t >> 6] = s;
    __syncthreads();
    if (t == 0) {
        float n = sqrtf(red[0] + red[1] + red[2] + red[3]);
        sscale = 1.0f / fmaxf(n, 1e-12f);
    }
    __syncthreads();
    float sc = sscale;
    x.x = f2bf(f0 * sc); x.y = f2bf(f1 * sc); x.z = f2bf(f2 * sc); x.w = f2bf(f3 * sc);
    v4[t] = x;
}

// ---------------------------------------------------------------------------
// colbert final reduce: out = sum_{i=1..127} dec(M[i,pb]) / masksum / TEMP
// one wave per (qb,pb) pair
// ---------------------------------------------------------------------------
__global__ void colbert_reduce_k(const unsigned* __restrict__ Mbuf,
                                 const float* __restrict__ q_mask,
                                 float* __restrict__ out)
{
    int pair = blockIdx.x * 4 + (threadIdx.x >> 6);
    int lane = threadIdx.x & 63;
    int qb = pair >> 6, pb = pair & 63;
    float s = 0.0f, msum = 0.0f;
    for (int i = 1 + lane; i < 128; i += 64) {
        s += decf(Mbuf[(qb * 128 + i) * 64 + pb]);
        msum += q_mask[qb * 128 + i];
    }
    #pragma unroll
    for (int sh = 32; sh; sh >>= 1) {
        s += __shfl_down(s, sh, 64);
        msum += __shfl_down(msum, sh, 64);
    }
    if (lane == 0) out[1024 + qb * 64 + pb] = s / msum / TEMP;
}

// ---------------------------------------------------------------------------
// dense: cosine of CLS tokens, fp32 exact. one block per (qb,pb)
// ---------------------------------------------------------------------------
__global__ void dense_scores_k(const float* __restrict__ qh, const float* __restrict__ ph,
                               float* __restrict__ out)
{
    __shared__ float red[12];
    int qb = blockIdx.x >> 6, pb = blockIdx.x & 63;
    int t = threadIdx.x;
    const float4* q4 = (const float4*)(qh + (size_t)qb * 128 * 1024);
    const float4* p4 = (const float4*)(ph + (size_t)pb * 512 * 1024);
    float4 a = q4[t], b = p4[t];
    float dot = a.x * b.x + a.y * b.y + a.z * b.z + a.w * b.w;
    float nq  = a.x * a.x + a.y * a.y + a.z * a.z + a.w * a.w;
    float np  = b.x * b.x + b.y * b.y + b.z * b.z + b.w * b.w;
    #pragma unroll
    for (int sh = 32; sh; sh >>= 1) {
        dot += __shfl_down(dot, sh, 64);
        nq  += __shfl_down(nq, sh, 64);
        np  += __shfl_down(np, sh, 64);
    }
    if ((t & 63) == 0) { int w = t >> 6; red[w] = dot; red[4 + w] = nq; red[8 + w] = np; }
    __syncthreads();
    if (t == 0) {
        dot = red[0] + red[1] + red[2] + red[3];
        nq  = red[4] + red[5] + red[6] + red[7];
        np  = red[8] + red[9] + red[10] + red[11];
        out[qb * 64 + pb] = dot / (fmaxf(sqrtf(nq), 1e-12f) * fmaxf(sqrtf(np), 1e-12f)) / TEMP;
    }
}

// ---------------------------------------------------------------------------
// sparse canonicalization: eff[row,l] = tw if token l is the (unique) argmax
// for its id within the row (ties -> lowest index) and id not in {0,1,2,3}
// throughput version: no break, no divergent loads -> compiler unrolls and
// pipelines the LDS reads (same-address across the wave = broadcast, free).
// grid = (rows, L/256); one token per thread.
// ---------------------------------------------------------------------------
template<int L>
__global__ void sparse_canon_k(const int* __restrict__ ids, const float* __restrict__ tw,
                               float* __restrict__ eff)
{
    __shared__ int   sid[L];
    __shared__ float stw[L];
    int row = blockIdx.x;
    int t = threadIdx.x;
    for (int l = t; l < L; l += 256) { sid[l] = ids[row * L + l]; stw[l] = tw[row * L + l]; }
    __syncthreads();
    int l = blockIdx.y * 256 + t;
    if (l < L) {
        int id = sid[l];
        float wv = stw[l];
        bool kill = (id < 4);  // UNUSED ids {0,1,2,3} -> zero
        #pragma unroll 8
        for (int m = 0; m < L; ++m) {
            int idm = sid[m];
            float wm = stw[m];
            bool beats = (idm == id) & (m != l) & ((wm > wv) | ((wm == wv) & (m < l)));
            kill = kill | beats;
        }
        eff[row * L + l] = kill ? 0.0f : wv;
    }
}

// ---------------------------------------------------------------------------
// sparse scores: sum over matching ids of q_eff * p_eff, one block per pair
// ---------------------------------------------------------------------------
__global__ void sparse_scores_k(const int* __restrict__ q_ids, const float* __restrict__ q_eff,
                                const int* __restrict__ p_ids, const float* __restrict__ p_eff,
                                float* __restrict__ out)
{
    __shared__ int   qid[128];
    __shared__ float qef[128];
    __shared__ int   pid[512];
    __shared__ float pef[512];
    __shared__ float red[4];
    int qb = blockIdx.x >> 6, pb = blockIdx.x & 63;
    int t = threadIdx.x;
    if (t < 128) { qid[t] = q_ids[qb * 128 + t]; qef[t] = q_eff[qb * 128 + t]; }
    for (int m = t; m < 512; m += 256) { pid[m] = p_ids[pb * 512 + m]; pef[m] = p_eff[pb * 512 + m]; }
    __syncthreads();
    float s = 0.0f;
    for (int idx = t; idx < 128 * 512; idx += 256) {
        int l = idx >> 9, m = idx & 511;
        if (qid[l] == pid[m]) s += qef[l] * pef[m];
    }
    #pragma unroll
    for (int sh = 32; sh; sh >>= 1) s += __shfl_down(s, sh, 64);
    if ((t & 63) == 0) red[t >> 6] = s;
    __syncthreads();
    if (t == 0) out[512 + qb * 64 + pb] = (red[0] + red[1] + red[2] + red[3]) / TEMP;
}

// ---------------------------------------------------------------------------
extern "C" void kernel_launch(void* const* d_in, const int* in_sizes, int n_in,
                              void* d_out, int out_size, void* d_ws, size_t ws_size,
                              hipStream_t stream)
{
    const float* q_hidden = (const float*)d_in[0];   // [8,128,1024]
    const float* p_hidden = (const float*)d_in[1];   // [64,512,1024]
    const float* q_mask   = (const float*)d_in[2];   // [8,128]
    const float* p_mask   = (const float*)d_in[3];   // [64,512]
    const int*   q_ids    = (const int*)d_in[4];     // [8,128]
    const int*   p_ids    = (const int*)d_in[5];     // [64,512]
    const float* colbert_w = (const float*)d_in[6];  // [1024,1024]
    const float* colbert_b = (const float*)d_in[7];  // [1024]
    const float* sparse_w  = (const float*)d_in[8];  // [1024]
    const float* sparse_b  = (const float*)d_in[9];  // [1]
    float* out = (float*)d_out;                      // [3*512]

    // workspace carve-up (~141 MB)
    char* ws = (char*)d_ws;
    size_t off = 0;
    auto carve = [&](size_t bytes) { char* p = ws + off; off += (bytes + 255) & ~(size_t)255; return p; };
    unsigned short* Wb   = (unsigned short*)carve((size_t)1024 * 1024 * 2);
    unsigned short* qhb  = (unsigned short*)carve((size_t)1024 * 1024 * 2);
    unsigned short* phb  = (unsigned short*)carve((size_t)32768 * 1024 * 2);
    unsigned short* qv   = (unsigned short*)carve((size_t)1024 * 1024 * 2);
    unsigned short* pv   = (unsigned short*)carve((size_t)32768 * 1024 * 2);
    float*    tw_q  = (float*)carve(1024 * 4);
    float*    tw_p  = (float*)carve(32768 * 4);
    float*    eff_q = (float*)carve(1024 * 4);
    float*    eff_p = (float*)carve(32768 * 4);
    unsigned* Mbuf  = (unsigned*)carve((size_t)1024 * 64 * 4);

    hipMemsetAsync(Mbuf, 0, (size_t)1024 * 64 * 4, stream);

    // bf16 conversions + sparse token weights
    conv_only<<<1024, 256, 0, stream>>>(colbert_w, Wb, 262144);
    conv_tw<<<1024, 256, 0, stream>>>(q_hidden, qhb, sparse_w, sparse_b, tw_q);
    conv_tw<<<32768, 256, 0, stream>>>(p_hidden, phb, sparse_w, sparse_b, tw_p);

    // colbert projection GEMMs: V = X @ W^T + b   (bf16 out)
    gemm_bt<0><<<dim3(8, 8), 256, 0, stream>>>(qhb, Wb, colbert_b, qv, nullptr, 1024, 1024, 1024);
    gemm_bt<0><<<dim3(8, 256), 256, 0, stream>>>(phb, Wb, colbert_b, pv, nullptr, 32768, 1024, 1024);

    // mask + L2 normalize rows in place
    normalize_rows_k<<<1024, 256, 0, stream>>>(qv, q_mask);
    normalize_rows_k<<<32768, 256, 0, stream>>>(pv, p_mask);

    // maxsim GEMM with fused max epilogue
    gemm_bt<1><<<dim3(256, 8), 256, 0, stream>>>(qv, pv, nullptr, nullptr, Mbuf, 1024, 32768, 1024);
    colbert_reduce_k<<<128, 256, 0, stream>>>(Mbuf, q_mask, out);

    // dense
    dense_scores_k<<<512, 256, 0, stream>>>(q_hidden, p_hidden, out);

    // sparse
    sparse_canon_k<128><<<dim3(8, 1), 256, 0, stream>>>(q_ids, tw_q, eff_q);
    sparse_canon_k<512><<<dim3(64, 2), 256, 0, stream>>>(p_ids, tw_p, eff_p);
    sparse_scores_k<<<512, 256, 0, stream>>>(q_ids, eff_q, p_ids, eff_p, out);
}